// Round 1
// 691.714 us; speedup vs baseline: 1.0159x; 1.0159x over previous
//
#include <hip/hip_runtime.h>

#define D_FEAT 64
#define M_LEN 32
#define BLOCK 512
#define MAXSEG 512
#define HALF_J 16
#define BIGF 1e30f

// One block per segment. Thread t owns column t of the segment.
// Phase 1 (no divergent CF -> q loads scalarize to s_load):
//   c[j] = sum_d q[d][j] * X[d][base+col], xx = sum_d x^2.
//   X loads: coalesced, nontemporal (streamed once), batched 8-deep for
//   latency hiding; q: wave-uniform address -> SMEM pipe, zero VGPR cost.
// Phase 2: h[j][t] = xx - 2*c[j] staged in LDS in TWO j-halves of 16 rows
//   (32 KB instead of 64 KB -> 4 blocks/CU instead of 2; occupancy was the
//   bottleneck, not LDS capacity). dist[p] = sum_j h[j][p+j] accumulated
//   across both halves (QQ dropped: additive const cancels in min-max scaling),
//   block-min -> mins[seg].
__global__ __launch_bounds__(BLOCK, 8) void seg_min_kernel(
    const float* __restrict__ X, const float* __restrict__ q,
    const int* __restrict__ cumlens, float* __restrict__ mins, long long T)
{
    __shared__ float h[HALF_J * MAXSEG];   // 32 KB -> 4 blocks/CU (wave-capped)

    const int seg  = blockIdx.x;
    const int base = cumlens[seg];
    const int len  = cumlens[seg + 1] - base;   // == 512 here; <= MAXSEG assumed
    const int tid  = threadIdx.x;
    // clamp instead of branch: keeps control flow uniform so q-loads scalarize;
    // clamped threads redundantly recompute column len-1 (benign same-value race)
    const int col  = tid < len ? tid : (len > 0 ? len - 1 : 0);

    float c[M_LEN];
    #pragma unroll
    for (int j = 0; j < M_LEN; ++j) c[j] = 0.0f;
    float xx = 0.0f;

    const float* xp = X + (size_t)base + (size_t)col;

    #pragma unroll 1   // keep rolled: bounds VGPR pressure (xv[8] in flight)
    for (int d0 = 0; d0 < D_FEAT; d0 += 8) {
        float xv[8];
        #pragma unroll
        for (int dd = 0; dd < 8; ++dd)
            xv[dd] = __builtin_nontemporal_load(xp + (size_t)(d0 + dd) * (size_t)T);

        #pragma unroll
        for (int dd = 0; dd < 8; ++dd) {
            const float x = xv[dd];
            xx = fmaf(x, x, xx);
            const float* __restrict__ qd = q + (d0 + dd) * M_LEN;  // uniform -> s_load
            #pragma unroll
            for (int j = 0; j < M_LEN; ++j)
                c[j] = fmaf(x, qd[j], c[j]);
        }
    }

    // ---- half A: j = 0..15 ----
    // h[j][t] = xx - 2*c[j]; per fixed j lanes are consecutive -> conflict-free
    #pragma unroll
    for (int j = 0; j < HALF_J; ++j)
        h[j * MAXSEG + col] = fmaf(-2.0f, c[j], xx);
    __syncthreads();

    const bool valid = (tid + M_LEN - 1 < len);   // valid window start: tid <= len - M
    float acc = 0.0f;
    if (valid) {
        #pragma unroll
        for (int j = 0; j < HALF_J; ++j)
            acc += h[j * MAXSEG + tid + j];   // fixed j: consecutive lanes -> conflict-free
    }
    __syncthreads();   // all reads of half A done before overwrite

    // ---- half B: j = 16..31 ----
    #pragma unroll
    for (int j = HALF_J; j < M_LEN; ++j)
        h[(j - HALF_J) * MAXSEG + col] = fmaf(-2.0f, c[j], xx);
    __syncthreads();

    float dist = BIGF;
    if (valid) {
        #pragma unroll
        for (int j = HALF_J; j < M_LEN; ++j)
            acc += h[(j - HALF_J) * MAXSEG + tid + j];
        dist = acc;
    }

    // wave (64-lane) min reduction
    #pragma unroll
    for (int off = 32; off > 0; off >>= 1)
        dist = fminf(dist, __shfl_down(dist, off));

    __syncthreads();                 // all h reads done; safe to reuse h as scratch
    if ((tid & 63) == 0) h[tid >> 6] = dist;
    __syncthreads();
    if (tid == 0) {
        float m = h[0];
        #pragma unroll
        for (int w = 1; w < BLOCK / 64; ++w) m = fminf(m, h[w]);
        mins[seg] = m;
    }
}

// Single block: lo/hi over mins, then out[i,k] = scaled[i]*w[k] + b[k]
__global__ __launch_bounds__(1024) void finalize_kernel(
    const float* __restrict__ mins, const float* __restrict__ lw,
    const float* __restrict__ lb, float* __restrict__ out, int nseg)
{
    __shared__ float slo[16], shi[16];
    const int tid = threadIdx.x;
    float lo = BIGF, hi = -BIGF;
    for (int i = tid; i < nseg; i += blockDim.x) {
        float v = mins[i];
        lo = fminf(lo, v);
        hi = fmaxf(hi, v);
    }
    #pragma unroll
    for (int off = 32; off > 0; off >>= 1) {
        lo = fminf(lo, __shfl_down(lo, off));
        hi = fmaxf(hi, __shfl_down(hi, off));
    }
    const int nw = blockDim.x >> 6;
    if ((tid & 63) == 0) { slo[tid >> 6] = lo; shi[tid >> 6] = hi; }
    __syncthreads();
    if (tid == 0) {
        float l = slo[0], h2 = shi[0];
        for (int w = 1; w < nw; ++w) { l = fminf(l, slo[w]); h2 = fmaxf(h2, shi[w]); }
        slo[0] = l; shi[0] = h2;
    }
    __syncthreads();
    lo = slo[0]; hi = shi[0];
    const float inv = 1.0f / (hi - lo + 1e-16f);
    const float w0 = lw[0], w1 = lw[1], b0 = lb[0], b1 = lb[1];
    for (int i = tid; i < nseg; i += blockDim.x) {
        float s = (mins[i] - lo) * inv;
        out[2 * i]     = fmaf(s, w0, b0);
        out[2 * i + 1] = fmaf(s, w1, b1);
    }
}

extern "C" void kernel_launch(void* const* d_in, const int* in_sizes, int n_in,
                              void* d_out, int out_size, void* d_ws, size_t ws_size,
                              hipStream_t stream) {
    const float* X   = (const float*)d_in[0];
    const float* q   = (const float*)d_in[1];
    const float* lw  = (const float*)d_in[2];
    const float* lb  = (const float*)d_in[3];
    const int*   cum = (const int*)d_in[4];

    const int n_seg = in_sizes[4] - 1;
    const long long T = (long long)in_sizes[0] / D_FEAT;

    float* mins = (float*)d_ws;          // n_seg floats, fully written each call
    float* out  = (float*)d_out;

    seg_min_kernel<<<n_seg, BLOCK, 0, stream>>>(X, q, cum, mins, T);
    finalize_kernel<<<1, 1024, 0, stream>>>(mins, lw, lb, out, n_seg);
}